// Round 13
// baseline (107.153 us; speedup 1.0000x reference)
//
#include <hip/hip_runtime.h>

#define A_TOTAL 34000

// 1024-thread (16-wave) blocks, 37 tiles x 16 batches = 592 blocks.
// Rationale (r12 post-mortem): all small-block variants tied at ~23us kernel;
// the untested axis is the per-block staging+barrier latency chain (paid per
// 128 anchors in v11/v12). Here it's paid once per 1024 anchors (8x), only
// waves 0-1 stage (others go straight to the barrier), and 592 near-uniform
// blocks = 9.25 waves/SIMD keep the machine full.
//   L0: 32x32 anchor tiles, 5x5=25 blocks/batch, s=4,  a=16,  base 0
//   L1: 32x32 tiles, 3x3=9 blocks/batch (edge-clamped), s=8, a=32, base 25600
//   L2: 2 flat 1024-chunks (y-band cull), s=16, a=64,  base 32000
//   L3: 1 flat chunk (k<400),             s=32, a=128, base 33600

__global__ __launch_bounds__(1024) void multi_anchor_encode_v13(
    const float* __restrict__ boxes,   // [B, 128, 4] yxyx f32
    float* __restrict__ out)           // [B, A_TOTAL, 5] f32
{
    __shared__ float4 cbox[128];   // compacted survivors, ascending box order
    __shared__ float  csum[128];   // area_a + area_box (pre-added, rn)
    __shared__ int    scnt;

    const int b    = blockIdx.y;
    const int t    = threadIdx.x;      // 0..1023
    const int bid  = blockIdx.x;       // 0..36
    const int w    = t >> 6;           // wave 0..15
    const int lane = t & 63;

    // ---- Anchor decode + block-uniform conservative tile bounds ----
    int   ia = 0, ja = 0, a_flat = 0;
    float s = 4.f, asize = 16.f;
    bool  valid = true;
    float ty0, ty1, tx0, tx1;

    if (bid < 25) {                        // L0: 32x32 tile
        int ty = bid / 5, tx = bid - ty * 5;
        int i0 = ty * 32, j0 = tx * 32;
        ia = i0 + (t >> 5); ja = j0 + (t & 31);
        s = 4.f; asize = 16.f;
        a_flat = ia * 160 + ja;
        ty0 = (float)(i0 * 4 - 8);  ty1 = (float)((i0 + 31) * 4 + 8);
        tx0 = (float)(j0 * 4 - 8);  tx1 = (float)((j0 + 31) * 4 + 8);
    } else if (bid < 34) {                 // L1: 32x32 tile (edge-clamped)
        int q = bid - 25; int ty = q / 3, tx = q - ty * 3;
        int i0 = ty * 32, j0 = tx * 32;
        ia = i0 + (t >> 5); ja = j0 + (t & 31);
        s = 8.f; asize = 32.f;
        valid = (ia < 80) && (ja < 80);
        int iaa = valid ? ia : 0, jaa = valid ? ja : 0;
        ia = iaa; ja = jaa;
        a_flat = 25600 + ia * 80 + ja;
        int ihi = (i0 + 31 < 79) ? i0 + 31 : 79;
        int jhi = (j0 + 31 < 79) ? j0 + 31 : 79;
        ty0 = (float)(i0 * 8 - 16); ty1 = (float)(ihi * 8 + 16);
        tx0 = (float)(j0 * 8 - 16); tx1 = (float)(jhi * 8 + 16);
    } else if (bid < 36) {                 // L2: flat 1024-chunks (y-band)
        int c = bid - 34; int k = c * 1024 + t;
        valid = (k < 1600); int kk = valid ? k : 0;
        ia = kk / 40; ja = kk - ia * 40;
        s = 16.f; asize = 64.f;
        a_flat = 32000 + kk;
        int klo = c * 1024, khi = (klo + 1023 < 1599) ? klo + 1023 : 1599;
        int ilo = klo / 40, ihi = khi / 40;
        ty0 = (float)(ilo * 16 - 32); ty1 = (float)(ihi * 16 + 32);
        tx0 = -1e30f; tx1 = 1e30f;
    } else {                               // L3: one flat chunk (k = t)
        int k = t;
        valid = (k < 400); int kk = valid ? k : 0;
        ia = kk / 20; ja = kk - ia * 20;
        s = 32.f; asize = 128.f;
        a_flat = 33600 + kk;
        ty0 = -64.f; ty1 = (float)(19 * 32 + 64);
        tx0 = -1e30f; tx1 = 1e30f;
    }

    const float area_a = asize * asize;    // exact (block-uniform)

    // ---- Staging: ONLY waves 0-1 (v11's proven scheme — each loads all 128
    // boxes, identical ballots; wave 0 compacts boxes 0..63, wave 1 compacts
    // 64..127; scnt published pre-barrier). Waves 2-15 go straight to the
    // barrier. Conservative >=/<= tests: a culled box provably has inter==0
    // with every anchor of this tile.
    const float4* bb = reinterpret_cast<const float4*>(boxes + (size_t)b * 128 * 4);
    if (w < 2) {
        float4 vA = bb[lane];              // x=ymin y=xmin z=ymax w=xmax
        float4 vB = bb[lane + 64];
        bool kA = (vA.z >= ty0) && (vA.x <= ty1) && (vA.w >= tx0) && (vA.y <= tx1);
        bool kB = (vB.z >= ty0) && (vB.x <= ty1) && (vB.w >= tx0) && (vB.y <= tx1);
        unsigned long long mA = __ballot(kA);
        unsigned long long mB = __ballot(kB);
        unsigned long long below = (1ull << lane) - 1ull;
        if (w == 0) {
            if (kA) {
                int p = __popcll(mA & below);
                cbox[p] = vA;
                csum[p] = __fadd_rn(area_a,
                          __fmul_rn(__fsub_rn(vA.z, vA.x), __fsub_rn(vA.w, vA.y)));
            }
        } else {
            if (kB) {
                int p = __popcll(mA) + __popcll(mB & below);
                cbox[p] = vB;
                csum[p] = __fadd_rn(area_a,
                          __fmul_rn(__fsub_rn(vB.z, vB.x), __fsub_rn(vB.w, vB.y)));
            }
        }
        if (t == 0) scnt = __popcll(mA) + __popcll(mB);
    }
    __syncthreads();                       // the ONLY barrier

    const float half = asize * 0.5f;       // exact (power of two)
    const float cy = (float)ia * s, cx = (float)ja * s;  // exact ints in f32
    const float ay0 = cy - half, ax0 = cx - half;
    const float ay1 = cy + half, ax1 = cx + half;
    const float inv = 1.0f / asize;        // exact power of two

    const int cnt = scnt;                  // wave-uniform LDS broadcast

    // ---- PASS 1 (v12, validated): branch-free approx scan; loop-carry is a
    // single fmax. rcp err <= ~2.5 ulp; 1e-6 rel slack provably contains the
    // exact argmax and all exact ties.
    float best_a = 0.0f;
    unsigned long long cm0 = 0ull, cm1 = 0ull;
    const int c64 = cnt < 64 ? cnt : 64;
    #pragma unroll 4
    for (int m = 0; m < c64; ++m) {
        float4 v  = cbox[m];
        float  su = csum[m];
        float ymin = fmaxf(ay0, v.x);
        float xmin = fmaxf(ax0, v.y);
        float ymax = fminf(ay1, v.z);
        float xmax = fminf(ax1, v.w);
        float ih   = fmaxf(__fsub_rn(ymax, ymin), 0.0f);
        float iw   = fmaxf(__fsub_rn(xmax, xmin), 0.0f);
        float inter = __fmul_rn(ih, iw);
        float denom = __fsub_rn(su, inter);
        float qa    = __fmul_rn(inter, __frcp_rn(denom));   // approx iou
        bool  cand  = qa > __fmul_rn(best_a, 0.999999f);
        cm0 |= cand ? (1ull << m) : 0ull;
        best_a = fmaxf(best_a, qa);
    }
    #pragma unroll 4
    for (int m = 64; m < cnt; ++m) {
        float4 v  = cbox[m];
        float  su = csum[m];
        float ymin = fmaxf(ay0, v.x);
        float xmin = fmaxf(ax0, v.y);
        float ymax = fminf(ay1, v.z);
        float xmax = fminf(ax1, v.w);
        float ih   = fmaxf(__fsub_rn(ymax, ymin), 0.0f);
        float iw   = fmaxf(__fsub_rn(xmax, xmin), 0.0f);
        float inter = __fmul_rn(ih, iw);
        float denom = __fsub_rn(su, inter);
        float qa    = __fmul_rn(inter, __frcp_rn(denom));
        bool  cand  = qa > __fmul_rn(best_a, 0.999999f);
        cm1 |= cand ? (1ull << (m - 64)) : 0ull;
        best_a = fmaxf(best_a, qa);
    }

    // ---- PASS 2: exact re-eval of candidates, ascending order -> first-max.
    // Accept path is the four-times-validated bit-exact numpy f32 chain.
    float best = 0.0f; int bl = -1;
    #pragma unroll 1
    for (int word = 0; word < 2; ++word) {
        unsigned long long cm = word ? cm1 : cm0;
        int jb = word << 6;
        while (cm) {
            int j = jb + (int)__builtin_ctzll(cm);
            cm &= cm - 1;
            float4 v  = cbox[j];
            float  su = csum[j];
            float ymin = fmaxf(ay0, v.x);
            float xmin = fmaxf(ax0, v.y);
            float ymax = fminf(ay1, v.z);
            float xmax = fminf(ax1, v.w);
            float ih   = fmaxf(__fsub_rn(ymax, ymin), 0.0f);
            float iw   = fmaxf(__fsub_rn(xmax, xmin), 0.0f);
            float inter = __fmul_rn(ih, iw);
            float denom = __fsub_rn(su, inter);
            float iou   = __fdiv_rn(inter, denom);   // IEEE == numpy f32
            if (iou > best) { best = iou; bl = j; }
        }
    }

    if (!valid) return;

    // Matched box: compacted entry, or original box 0 if all IoU == 0
    // (np.argmax of all-zero row -> 0; box 0 may be culled -> global re-read).
    float4 mbx;
    if (bl >= 0) mbx = cbox[bl];           // per-lane ds_read, exec-safe
    else         mbx = bb[0];              // L1/L2-hot, exec-safe
    float mcy = __fmul_rn(__fadd_rn(mbx.x, mbx.z), 0.5f);
    float mcx = __fmul_rn(__fadd_rn(mbx.y, mbx.w), 0.5f);
    float mh  = __fsub_rn(mbx.z, mbx.x);
    float mw  = __fsub_rn(mbx.w, mbx.y);

    size_t o = ((size_t)b * A_TOTAL + a_flat) * 5;
    out[o + 0] = best;
    out[o + 1] = __fmul_rn(__fsub_rn(mcy, cy), inv);
    out[o + 2] = __fmul_rn(__fsub_rn(mcx, cx), inv);
    out[o + 3] = __fmul_rn(__fsub_rn(mh, asize), inv);
    out[o + 4] = __fmul_rn(__fsub_rn(mw, asize), inv);
}

extern "C" void kernel_launch(void* const* d_in, const int* in_sizes, int n_in,
                              void* d_out, int out_size, void* d_ws, size_t ws_size,
                              hipStream_t stream) {
    const float* boxes = (const float*)d_in[0];
    float* out = (float*)d_out;
    dim3 grid(37, 16 /*B*/);
    multi_anchor_encode_v13<<<grid, 1024, 0, stream>>>(boxes, out);
}

// Round 15
// 74.572 us; speedup vs baseline: 1.4369x; 1.4369x over previous
//
#include <hip/hip_runtime.h>

#define A_TOTAL 34000

// v14: 2048 single-wave blocks (64 thr), ZERO LDS, ZERO barriers.
// Rationale: every prior sub-40us variant launched 8.5-9.5K waves > ~8.2K
// resident slots -> block backfill churn; measured Occ 4.6-16% says the
// machine idles while blocks cycle. Here all 2048 waves (8 blocks/CU) are
// resident from t=0; each wave stages its batch's 128 boxes into REGISTERS
// once and processes 4-5 work units (532 units/batch):
//   u <400 : L0 16x4 tile  (40 ty x 10 tx), s=4,  a=16,  base 0
//   u <500 : L1 16x4 tile  (20 ty x  5 tx), s=8,  a=32,  base 25600
//   u <525 : L2 flat 64-chunk (y-band),     s=16, a=64,  base 32000
//   u <532 : L3 flat 64-chunk (y-band),     s=32, a=128, base 33600
// Walk = v8's validated readlane walk (zero memory ops) + v6's validated
// one-sided mul filter; epilogue = v8's exec-safe bb[bi] gather. All pieces
// individually absmax-0.0 proven.

__device__ __forceinline__ float rdlane(float v, int l) {
    return __int_as_float(__builtin_amdgcn_readlane(__float_as_int(v), l));
}

__global__ __launch_bounds__(64) void multi_anchor_encode_v14(
    const float* __restrict__ boxes,   // [B, 128, 4] yxyx f32
    float* __restrict__ out)           // [B, A_TOTAL, 5] f32
{
    const int wid  = blockIdx.x;       // 0..2047
    const int bt   = wid >> 7;         // batch 0..15
    const int r    = wid & 127;        // work lane within batch
    const int lane = threadIdx.x;      // 0..63

    // ---- Stage all 128 boxes of this wave's batch into registers, ONCE ----
    const float4* bb = reinterpret_cast<const float4*>(boxes + (size_t)bt * 128 * 4);
    float4 vA = bb[lane];              // x=ymin y=xmin z=ymax w=xmax
    float4 vB = bb[lane + 64];
    float arA = __fmul_rn(__fsub_rn(vA.z, vA.x), __fsub_rn(vA.w, vA.y));
    float arB = __fmul_rn(__fsub_rn(vB.z, vB.x), __fsub_rn(vB.w, vB.y));

    // ---- Grid-stride over this wave's 4-5 units (u = r, r+128, ..., <532) ----
    for (int uu = 0; uu < 5; ++uu) {
        const int u = r + (uu << 7);
        if (u >= 532) break;           // wave-uniform (r is wave-uniform)

        int   ia, ja, a_flat;
        float s, asize;
        bool  valid = true;
        float ty0, ty1, tx0, tx1;

        if (u < 400) {                 // L0: 16 cols x 4 rows
            int ty = u / 10, tx = u - ty * 10;
            int i0 = ty * 4, j0 = tx * 16;
            ia = i0 + (lane >> 4); ja = j0 + (lane & 15);
            s = 4.f; asize = 16.f;
            a_flat = ia * 160 + ja;
            ty0 = (float)(i0 * 4 - 8);  ty1 = (float)((i0 + 3) * 4 + 8);
            tx0 = (float)(j0 * 4 - 8);  tx1 = (float)((j0 + 15) * 4 + 8);
        } else if (u < 500) {          // L1: 16 cols x 4 rows
            int q = u - 400;
            int ty = q / 5, tx = q - ty * 5;
            int i0 = ty * 4, j0 = tx * 16;
            ia = i0 + (lane >> 4); ja = j0 + (lane & 15);
            s = 8.f; asize = 32.f;
            a_flat = 25600 + ia * 80 + ja;
            ty0 = (float)(i0 * 8 - 16); ty1 = (float)((i0 + 3) * 8 + 16);
            tx0 = (float)(j0 * 8 - 16); tx1 = (float)((j0 + 15) * 8 + 16);
        } else if (u < 525) {          // L2: flat 64-chunk (y-band cull)
            int q = u - 500; int k = (q << 6) + lane;   // 0..1599, all valid
            ia = k / 40; ja = k - ia * 40;
            s = 16.f; asize = 64.f;
            a_flat = 32000 + k;
            int ilo = (q << 6) / 40, ihi = ((q << 6) + 63) / 40;
            ty0 = (float)(ilo * 16 - 32); ty1 = (float)(ihi * 16 + 32);
            tx0 = -1e30f; tx1 = 1e30f;
        } else {                       // L3: flat 64-chunk (y-band cull)
            int q = u - 525; int k = (q << 6) + lane;
            valid = (k < 400); int kk = valid ? k : 0;
            ia = kk / 20; ja = kk - ia * 20;
            s = 32.f; asize = 128.f;
            a_flat = 33600 + kk;
            int klo = q << 6, khi = (klo + 63 < 399) ? klo + 63 : 399;
            int ilo = klo / 20, ihi = khi / 20;
            ty0 = (float)(ilo * 32 - 64); ty1 = (float)(ihi * 32 + 64);
            tx0 = -1e30f; tx1 = 1e30f;
        }

        // ---- Cull (wave-uniform bounds -> masks valid for the whole wave).
        // Conservative >=/<=: culled box provably has inter==0 w/ every anchor.
        bool kA = (vA.z >= ty0) && (vA.x <= ty1) && (vA.w >= tx0) && (vA.y <= tx1);
        bool kB = (vB.z >= ty0) && (vB.x <= ty1) && (vB.w >= tx0) && (vB.y <= tx1);
        unsigned long long mA = __ballot(kA);
        unsigned long long mB = __ballot(kB);

        const float area_a = asize * asize;            // exact
        const float half   = asize * 0.5f;             // exact
        const float cy = (float)ia * s, cx = (float)ja * s;  // exact ints
        const float ay0 = cy - half, ax0 = cx - half;
        const float ay1 = cy + half, ax1 = cx + half;
        const float inv = 1.0f / asize;                // exact power of two

        // ---- Ordered survivor walk, zero memory ops (v8-validated).
        // best=0/bi=0 == np.argmax (all-zero row -> 0; else first max; j
        // ascends; accept-path rn chain bit-identical to numpy f32).
        // v6-validated one-sided filter: iou>best requires
        // inter > best*denom*(1-2^-24); 0.9999995 factor is strictly looser,
        // so skips are provably safe; fdiv confirm keeps numpy's decision.
        float best = 0.0f; int bi = 0;
#define WALK(MASKW, LBASE, JBASE, VV, AR)                                     \
        {                                                                     \
            unsigned int m = (unsigned int)__builtin_amdgcn_readfirstlane(MASKW); \
            while (m) {                                                       \
                int l32 = __builtin_ctz(m); m &= m - 1;                       \
                int ln = LBASE + l32;                                         \
                float bx0 = rdlane(VV.x, ln);                                 \
                float bx1 = rdlane(VV.y, ln);                                 \
                float bx2 = rdlane(VV.z, ln);                                 \
                float bx3 = rdlane(VV.w, ln);                                 \
                float sa  = rdlane(AR, ln);                                   \
                float ymin = fmaxf(ay0, bx0);                                 \
                float xmin = fmaxf(ax0, bx1);                                 \
                float ymax = fminf(ay1, bx2);                                 \
                float xmax = fminf(ax1, bx3);                                 \
                float ih   = fmaxf(__fsub_rn(ymax, ymin), 0.0f);              \
                float iw   = fmaxf(__fsub_rn(xmax, xmin), 0.0f);              \
                float inter = __fmul_rn(ih, iw);                              \
                float denom = __fsub_rn(__fadd_rn(area_a, sa), inter);        \
                float thr   = __fmul_rn(__fmul_rn(best, denom), 0.9999995f);  \
                if (inter > thr) {                                            \
                    float iou = __fdiv_rn(inter, denom); /* IEEE == numpy */  \
                    if (iou > best) { best = iou; bi = JBASE + l32; }         \
                }                                                             \
            }                                                                 \
        }
        WALK((unsigned int)mA,         0,  0, vA, arA)
        WALK((unsigned int)(mA >> 32), 32, 32, vA, arA)
        WALK((unsigned int)mB,         0,  64, vB, arB)
        WALK((unsigned int)(mB >> 32), 32, 96, vB, arB)
#undef WALK

        if (valid) {
            // Matched box via direct global load (L1-hot, exec-safe; bi==0
            // when all IoU==0 == np.argmax of an all-zero row). v8-validated.
            float4 mbx = bb[bi];
            float mcy = __fmul_rn(__fadd_rn(mbx.x, mbx.z), 0.5f);
            float mcx = __fmul_rn(__fadd_rn(mbx.y, mbx.w), 0.5f);
            float mh  = __fsub_rn(mbx.z, mbx.x);
            float mw  = __fsub_rn(mbx.w, mbx.y);

            size_t o = ((size_t)bt * A_TOTAL + a_flat) * 5;
            out[o + 0] = best;
            out[o + 1] = __fmul_rn(__fsub_rn(mcy, cy), inv);
            out[o + 2] = __fmul_rn(__fsub_rn(mcx, cx), inv);
            out[o + 3] = __fmul_rn(__fsub_rn(mh, asize), inv);
            out[o + 4] = __fmul_rn(__fsub_rn(mw, asize), inv);
        }
    }
}

extern "C" void kernel_launch(void* const* d_in, const int* in_sizes, int n_in,
                              void* d_out, int out_size, void* d_ws, size_t ws_size,
                              hipStream_t stream) {
    const float* boxes = (const float*)d_in[0];
    float* out = (float*)d_out;
    multi_anchor_encode_v14<<<dim3(2048), 64, 0, stream>>>(boxes, out);
}